// Round 2
// baseline (1498.902 us; speedup 1.0000x reference)
//
#include <hip/hip_runtime.h>

#define DIN 4096
#define DOUT 64
#define SEQ 2048
#define NADPT 16

typedef __bf16 bf16x8 __attribute__((ext_vector_type(8)));
typedef float f32x4 __attribute__((ext_vector_type(4)));

// ---------------------------------------------------------------------------
// Kernel 1: one-shot weight transpose+convert.
//   weight[a][k][n] fp32  ->  wT[a][n][k] bf16   (wT lives in d_ws, 8 MB)
// Reads coalesced over n (64 fp32 = 256 B per k-row); writes 16 B bf16x8.
// Runs every launch (harness re-poisons d_ws); ~25 MB traffic ≈ 5 us.
// ---------------------------------------------------------------------------
__global__ __launch_bounds__(256)
void transpose_w_kernel(const float* __restrict__ w, __bf16* __restrict__ wT)
{
    const int a  = blockIdx.y;
    const int k0 = blockIdx.x * 32 + (threadIdx.x >> 6) * 8;  // 4 k8-chunks/block
    const int n  = threadIdx.x & 63;
    const float* src = w + ((size_t)a * DIN + k0) * DOUT + n;
    bf16x8 v;
#pragma unroll
    for (int j = 0; j < 8; ++j)
        v[j] = (__bf16)src[(size_t)j * DOUT];
    *(bf16x8*)(wT + ((size_t)a * DOUT + n) * DIN + k0) = v;
}

// ---------------------------------------------------------------------------
// Kernel 2: main GEMM. No LDS, no barriers.
// Block = 64 rows x 64 cols, 4 waves; wave owns 16 rows, all N=64 (4 n-tiles).
// A-frag: lane(m=lane&15) reads 8 consecutive fp32 from its x row (xa+xb
//   together fully cover 128B lines -> no HBM over-fetch), cvt to bf16.
// B-frag: direct bf16x8 global load from pre-transposed wT (L2-resident).
// C/D layout (verified r1): col = lane&15, row = quad*4 + reg.
// ---------------------------------------------------------------------------
__global__ __launch_bounds__(256, 4)
void lora_gemm_kernel(const float* __restrict__ x,
                      const int* __restrict__ adapter_ids,
                      const __bf16* __restrict__ wT,
                      float* __restrict__ out)
{
    const int row0 = blockIdx.x * 64;            // 64 | SEQ -> one b per block
    const int aid  = adapter_ids[row0 / SEQ];

    const int tid  = threadIdx.x;
    const int wave = tid >> 6;
    const int lane = tid & 63;
    const int m16  = lane & 15;
    const int quad = lane >> 4;

    const float*  xrow = x  + (size_t)(row0 + wave * 16 + m16) * DIN + quad * 8;
    const __bf16* wb   = wT + ((size_t)aid * DOUT + m16) * DIN + quad * 8;

    f32x4 acc[4];
#pragma unroll
    for (int t = 0; t < 4; ++t) acc[t] = (f32x4)0.0f;

#pragma unroll 2
    for (int k = 0; k < DIN; k += 32) {
        const f32x4 xa = *(const f32x4*)(xrow + k);
        const f32x4 xb = *(const f32x4*)(xrow + k + 4);
        bf16x8 a;
        a[0] = (__bf16)xa[0]; a[1] = (__bf16)xa[1];
        a[2] = (__bf16)xa[2]; a[3] = (__bf16)xa[3];
        a[4] = (__bf16)xb[0]; a[5] = (__bf16)xb[1];
        a[6] = (__bf16)xb[2]; a[7] = (__bf16)xb[3];
#pragma unroll
        for (int t = 0; t < 4; ++t) {
            const bf16x8 bf = *(const bf16x8*)(wb + (size_t)t * 16 * DIN + k);
            acc[t] = __builtin_amdgcn_mfma_f32_16x16x32_bf16(a, bf, acc[t], 0, 0, 0);
        }
    }

    float* obase = out + (size_t)(row0 + wave * 16 + quad * 4) * DOUT + m16;
#pragma unroll
    for (int i = 0; i < 4; ++i)
#pragma unroll
        for (int t = 0; t < 4; ++t)
            obase[(size_t)i * DOUT + t * 16] = acc[t][i];
}

extern "C" void kernel_launch(void* const* d_in, const int* in_sizes, int n_in,
                              void* d_out, int out_size, void* d_ws, size_t ws_size,
                              hipStream_t stream) {
    const float* x   = (const float*)d_in[0];
    const int*   ids = (const int*)d_in[1];
    const float* w   = (const float*)d_in[2];
    float* out = (float*)d_out;
    __bf16* wT = (__bf16*)d_ws;                 // 16*64*4096*2 = 8 MB

    dim3 tgrid(DIN / 32, NADPT);                // 128 x 16 blocks
    transpose_w_kernel<<<tgrid, 256, 0, stream>>>(w, wT);

    const int total_rows = 32 * SEQ;            // 65536
    lora_gemm_kernel<<<dim3(total_rows / 64), 256, 0, stream>>>(x, ids, wT, out);
}